// Round 1
// baseline (633.535 us; speedup 1.0000x reference)
//
#include <hip/hip_runtime.h>
#include <stdint.h>

// ---------------- problem constants ----------------
#define B_ROWS   16384
#define D_IN     512
#define N_DIM    1024
#define NREL     16
#define TM       128
#define TN       128
#define BK       32
#define MAX_TILES 144                 // <= B_ROWS/TM + NREL-1 padding tiles
#define PADDED_ROWS (MAX_TILES * TM)  // 18432

typedef __bf16 bf16x8 __attribute__((ext_vector_type(8)));
typedef float  f32x4  __attribute__((ext_vector_type(4)));

__device__ __forceinline__ uint16_t f2bf(float f) {
  union { float f; uint32_t u; } v; v.f = f;
  return (uint16_t)((v.u + 0x7fffu + ((v.u >> 16) & 1u)) >> 16);   // RNE
}

// async global->LDS 16B copy. LDS dest must be (wave-uniform base + lane*16).
__device__ __forceinline__ void async_cp16(const uint16_t* g, uint16_t* l) {
  __builtin_amdgcn_global_load_lds(
      (__attribute__((address_space(1))) void*)(g),
      (__attribute__((address_space(3))) void*)(l), 16, 0, 0);
}

// ---------------- setup: histogram relations, build padded permutation ----------------
__global__ void setup_kernel(const int* __restrict__ rel, int* __restrict__ rowidx,
                             int* __restrict__ texp, int* __restrict__ tval) {
  __shared__ int cnt[NREL], segstart[NREL], cursor[NREL];
  const int t = threadIdx.x;
  if (t < NREL) { cnt[t] = 0; cursor[t] = 0; }
  __syncthreads();
  for (int i = t; i < B_ROWS; i += 256) atomicAdd(&cnt[rel[i]], 1);
  __syncthreads();
  if (t == 0) {
    int slot = 0, tile = 0;
    for (int r = 0; r < NREL; r++) {
      segstart[r] = slot;
      const int c = cnt[r];
      const int nt = (c + TM - 1) / TM;
      for (int k = 0; k < nt; k++) {
        texp[tile + k] = r;
        const int rem = c - k * TM;
        tval[tile + k] = rem < TM ? rem : TM;
      }
      tile += nt; slot += nt * TM;
    }
    for (; tile < MAX_TILES; tile++) { texp[tile] = 0; tval[tile] = 0; }
  }
  __syncthreads();
  for (int i = t; i < PADDED_ROWS; i += 256) rowidx[i] = 0;  // padded slots -> row 0 (safe loads)
  __syncthreads();
  for (int i = t; i < B_ROWS; i += 256) {
    const int r = rel[i];
    const int p = atomicAdd(&cursor[r], 1);
    rowidx[segstart[r] + p] = i;
  }
}

// ---------------- fp32 -> bf16 elementwise (x) ----------------
__global__ void conv_x_kernel(const float* __restrict__ in, uint16_t* __restrict__ out, int n4) {
  const int i = blockIdx.x * blockDim.x + threadIdx.x;
  if (i < n4) {
    const float4 v = ((const float4*)in)[i];
    uint2 o;
    o.x = (uint32_t)f2bf(v.x) | ((uint32_t)f2bf(v.y) << 16);
    o.y = (uint32_t)f2bf(v.z) | ((uint32_t)f2bf(v.w) << 16);
    ((uint2*)out)[i] = o;
  }
}

// ---------------- W[K][N] fp32 -> Wt[N][K] bf16 (batched over experts) ----------------
__global__ void transpose_conv_kernel(const float* __restrict__ W, uint16_t* __restrict__ Wt,
                                      int K, int N) {
  __shared__ uint16_t tile[32][33];
  const size_t mat = (size_t)K * N;
  const float*    Wp  = W  + mat * blockIdx.z;
  uint16_t*       Wtp = Wt + mat * blockIdx.z;
  const int n0 = blockIdx.x * 32, k0 = blockIdx.y * 32;
  const int tx = threadIdx.x & 31, ty = threadIdx.x >> 5;   // 256 thr: ty 0..7
  #pragma unroll
  for (int kk = ty; kk < 32; kk += 8)
    tile[kk][tx] = f2bf(Wp[(size_t)(k0 + kk) * N + n0 + tx]);
  __syncthreads();
  #pragma unroll
  for (int nn = ty; nn < 32; nn += 8)
    Wtp[(size_t)(n0 + nn) * K + k0 + tx] = tile[tx][nn];
}

// ---------------- the GEMM: C = [relu](A @ Wt^T + bias), m97-style 128x128xBK32 ----------------
// A: [rowsA][K] bf16 (optionally gathered via rowidx). Wt: [E][N][K] bf16 (pre-transposed).
// out: bf16 [Mpad][N]  or  (SCATTER) fp32 [B_ROWS][N] via rowidx with valid-mask.
template<bool GATHER, bool EXPERT, bool RELU, bool SCATTER>
__global__ __launch_bounds__(256)
void gemm_kernel(const uint16_t* __restrict__ A, const uint16_t* __restrict__ W,
                 const float* __restrict__ bias, void* __restrict__ outp,
                 const int* __restrict__ rowidx, const int* __restrict__ texp,
                 const int* __restrict__ tval, int K) {
  __shared__ uint16_t sA[TM * BK];
  __shared__ uint16_t sB[TN * BK];

  const int tid = threadIdx.x;
  const int w = tid >> 6, l = tid & 63;
  const int m0 = blockIdx.y * TM;
  const int n0 = blockIdx.x * TN;

  int e = 0, valid = TM;
  if (EXPERT) {
    e = texp[blockIdx.y];
    valid = tval[blockIdx.y];
    if (valid == 0) return;            // fully-padded tile: nothing downstream reads it unmasked
  }

  // staging assignment: wave w fills 1KB LDS chunks; lane l -> row p*64+16w+(l>>2), k (l&3)*8
  const int lrow0 = 16 * w + (l >> 2);
  const int lrow1 = 64 + lrow0;
  const int koff  = (l & 3) * 8;
  int ar0 = m0 + lrow0, ar1 = m0 + lrow1;
  if (GATHER) { ar0 = rowidx[ar0]; ar1 = rowidx[ar1]; }
  const uint16_t* srcA0 = A + (size_t)ar0 * K + koff;
  const uint16_t* srcA1 = A + (size_t)ar1 * K + koff;
  const uint16_t* Wb    = W + (size_t)e * N_DIM * K;
  const uint16_t* srcB0 = Wb + (size_t)(n0 + lrow0) * K + koff;
  const uint16_t* srcB1 = Wb + (size_t)(n0 + lrow1) * K + koff;
  uint16_t* ldsA0 = &sA[w * 512 + l * 8];
  uint16_t* ldsA1 = &sA[2048 + w * 512 + l * 8];
  uint16_t* ldsB0 = &sB[w * 512 + l * 8];
  uint16_t* ldsB1 = &sB[2048 + w * 512 + l * 8];

  const int wm = w >> 1, wn = w & 1;        // 2x2 waves, each 64x64
  const int q = l >> 4, r16 = l & 15;

  f32x4 acc[4][4];
  #pragma unroll
  for (int i = 0; i < 4; i++)
    #pragma unroll
    for (int j = 0; j < 4; j++) {
      f32x4 z = {0.f, 0.f, 0.f, 0.f};
      acc[i][j] = z;
    }

  for (int k0 = 0; k0 < K; k0 += BK) {
    async_cp16(srcA0 + k0, ldsA0);
    async_cp16(srcA1 + k0, ldsA1);
    async_cp16(srcB0 + k0, ldsB0);
    async_cp16(srcB1 + k0, ldsB1);
    __syncthreads();                       // drains vmcnt -> LDS tiles complete
    bf16x8 af[4], bf[4];
    #pragma unroll
    for (int i = 0; i < 4; i++) {
      af[i] = *(const bf16x8*)(&sA[(wm * 64 + i * 16 + r16) * BK + q * 8]);
      bf[i] = *(const bf16x8*)(&sB[(wn * 64 + i * 16 + r16) * BK + q * 8]);
    }
    #pragma unroll
    for (int i = 0; i < 4; i++)
      #pragma unroll
      for (int j = 0; j < 4; j++)
        acc[i][j] = __builtin_amdgcn_mfma_f32_16x16x32_bf16(af[i], bf[j], acc[i][j], 0, 0, 0);
    __syncthreads();                       // protect LDS before next overwrite
  }

  // epilogue: C/D layout col=lane&15, row=(lane>>4)*4+reg (m89/m91-verified)
  float bj[4];
  #pragma unroll
  for (int j = 0; j < 4; j++)
    bj[j] = bias[(size_t)e * N_DIM + n0 + wn * 64 + j * 16 + r16];

  #pragma unroll
  for (int i = 0; i < 4; i++) {
    #pragma unroll
    for (int r = 0; r < 4; r++) {
      const int rl = wm * 64 + i * 16 + q * 4 + r;        // row within 128-tile
      if (SCATTER) {
        if (rl < valid) {
          const int orow = rowidx[m0 + rl];
          float* o = (float*)outp + (size_t)orow * N_DIM + n0 + wn * 64 + r16;
          #pragma unroll
          for (int j = 0; j < 4; j++) {
            float v = acc[i][j][r] + bj[j];
            if (RELU) v = fmaxf(v, 0.f);
            o[j * 16] = v;
          }
        }
      } else {
        uint16_t* o = (uint16_t*)outp + (size_t)(m0 + rl) * N_DIM + n0 + wn * 64 + r16;
        #pragma unroll
        for (int j = 0; j < 4; j++) {
          float v = acc[i][j][r] + bj[j];
          if (RELU) v = fmaxf(v, 0.f);
          o[j * 16] = f2bf(v);
        }
      }
    }
  }
}

// ---------------- launch ----------------
extern "C" void kernel_launch(void* const* d_in, const int* in_sizes, int n_in,
                              void* d_out, int out_size, void* d_ws, size_t ws_size,
                              hipStream_t stream) {
  const float* x   = (const float*)d_in[0];
  const int*   rel = (const int*)d_in[1];
  const float* W0  = (const float*)d_in[2];
  const float* b0  = (const float*)d_in[3];
  const float* W1  = (const float*)d_in[4];
  const float* b1  = (const float*)d_in[5];
  const float* RW1 = (const float*)d_in[6];
  const float* Rb1 = (const float*)d_in[7];
  const float* RW2 = (const float*)d_in[8];
  const float* Rb2 = (const float*)d_in[9];
  const float* RW3 = (const float*)d_in[10];
  const float* Rb3 = (const float*)d_in[11];
  float* out = (float*)d_out;

  // workspace layout (bytes): xb 16MB | wt 32MB | ha 36MB | hb 36MB | rowidx/meta
  char* ws = (char*)d_ws;
  uint16_t* xb = (uint16_t*)(ws);
  uint16_t* wt = (uint16_t*)(ws + (size_t)(16u << 20));
  uint16_t* ha = (uint16_t*)(ws + (size_t)(48u << 20));
  uint16_t* hb = (uint16_t*)(ws + (size_t)(84u << 20));
  int* rowidx = (int*)(ws + (size_t)(120u << 20));
  int* texp   = rowidx + PADDED_ROWS;
  int* tval   = texp + MAX_TILES;

  const dim3 blk(256);
  const dim3 gDense(N_DIM / TN, B_ROWS / TM);     // 8 x 128
  const dim3 gRel(N_DIM / TN, MAX_TILES);         // 8 x 144

  setup_kernel<<<dim3(1), blk, 0, stream>>>(rel, rowidx, texp, tval);
  conv_x_kernel<<<dim3((B_ROWS * D_IN) / 4 / 256), blk, 0, stream>>>(x, xb, (B_ROWS * D_IN) / 4);

  // L0: h = relu(x @ W0 + b0), K=512
  transpose_conv_kernel<<<dim3(N_DIM / 32, D_IN / 32, 1), blk, 0, stream>>>(W0, wt, D_IN, N_DIM);
  gemm_kernel<false, false, true, false><<<gDense, blk, 0, stream>>>(
      xb, wt, b0, ha, nullptr, nullptr, nullptr, D_IN);

  // L1: h = relu(h @ W1 + b1), K=1024
  transpose_conv_kernel<<<dim3(N_DIM / 32, N_DIM / 32, 1), blk, 0, stream>>>(W1, wt, N_DIM, N_DIM);
  gemm_kernel<false, false, true, false><<<gDense, blk, 0, stream>>>(
      ha, wt, b1, hb, nullptr, nullptr, nullptr, N_DIM);

  // L2: gather rows by relation, relu(h @ RW1[r] + Rb1[r]) -> padded layout
  transpose_conv_kernel<<<dim3(N_DIM / 32, N_DIM / 32, NREL), blk, 0, stream>>>(RW1, wt, N_DIM, N_DIM);
  gemm_kernel<true, true, true, false><<<gRel, blk, 0, stream>>>(
      hb, wt, Rb1, ha, rowidx, texp, tval, N_DIM);

  // L3: relu(h @ RW2[r] + Rb2[r]) in padded layout
  transpose_conv_kernel<<<dim3(N_DIM / 32, N_DIM / 32, NREL), blk, 0, stream>>>(RW2, wt, N_DIM, N_DIM);
  gemm_kernel<false, true, true, false><<<gRel, blk, 0, stream>>>(
      ha, wt, Rb2, hb, rowidx, texp, tval, N_DIM);

  // L4: out[orig_row] = h @ RW3[r] + Rb3[r], fp32 scatter, no relu
  transpose_conv_kernel<<<dim3(N_DIM / 32, N_DIM / 32, NREL), blk, 0, stream>>>(RW3, wt, N_DIM, N_DIM);
  gemm_kernel<false, true, false, true><<<gRel, blk, 0, stream>>>(
      hb, wt, Rb3, out, rowidx, texp, tval, N_DIM);

  (void)in_sizes; (void)n_in; (void)out_size; (void)ws_size;
}

// Round 2
// 574.175 us; speedup vs baseline: 1.1034x; 1.1034x over previous
//
#include <hip/hip_runtime.h>
#include <stdint.h>

// ---------------- problem constants ----------------
#define B_ROWS   16384
#define D_IN     512
#define N_DIM    1024
#define NREL     16
#define TM       128
#define TN       128
#define BK       32
#define MAX_TILES 144                 // <= B_ROWS/TM + NREL-1 padding tiles
#define PADDED_ROWS (MAX_TILES * TM)  // 18432

typedef __bf16 bf16x8 __attribute__((ext_vector_type(8)));
typedef float  f32x4  __attribute__((ext_vector_type(4)));

__device__ __forceinline__ uint16_t f2bf(float f) {
  union { float f; uint32_t u; } v; v.f = f;
  return (uint16_t)((v.u + 0x7fffu + ((v.u >> 16) & 1u)) >> 16);   // RNE
}

// async global->LDS 16B copy. LDS dest must be (wave-uniform base + lane*16).
__device__ __forceinline__ void async_cp16(const uint16_t* g, uint16_t* l) {
  __builtin_amdgcn_global_load_lds(
      (__attribute__((address_space(1))) void*)(g),
      (__attribute__((address_space(3))) void*)(l), 16, 0, 0);
}

// ---------------- setup: histogram relations, build padded permutation ----------------
__global__ void setup_kernel(const int* __restrict__ rel, int* __restrict__ rowidx,
                             int* __restrict__ texp, int* __restrict__ tval) {
  __shared__ int cnt[NREL], segstart[NREL], cursor[NREL];
  const int t = threadIdx.x;
  if (t < NREL) { cnt[t] = 0; cursor[t] = 0; }
  __syncthreads();
  for (int i = t; i < B_ROWS; i += 256) atomicAdd(&cnt[rel[i]], 1);
  __syncthreads();
  if (t == 0) {
    int slot = 0, tile = 0;
    for (int r = 0; r < NREL; r++) {
      segstart[r] = slot;
      const int c = cnt[r];
      const int nt = (c + TM - 1) / TM;
      for (int k = 0; k < nt; k++) {
        texp[tile + k] = r;
        const int rem = c - k * TM;
        tval[tile + k] = rem < TM ? rem : TM;
      }
      tile += nt; slot += nt * TM;
    }
    for (; tile < MAX_TILES; tile++) { texp[tile] = 0; tval[tile] = 0; }
  }
  __syncthreads();
  for (int i = t; i < PADDED_ROWS; i += 256) rowidx[i] = 0;  // padded slots -> row 0 (safe loads)
  __syncthreads();
  for (int i = t; i < B_ROWS; i += 256) {
    const int r = rel[i];
    const int p = atomicAdd(&cursor[r], 1);
    rowidx[segstart[r] + p] = i;
  }
}

// ---------------- fp32 -> bf16 elementwise (x) ----------------
__global__ void conv_x_kernel(const float* __restrict__ in, uint16_t* __restrict__ out, int n4) {
  const int i = blockIdx.x * blockDim.x + threadIdx.x;
  if (i < n4) {
    const float4 v = ((const float4*)in)[i];
    uint2 o;
    o.x = (uint32_t)f2bf(v.x) | ((uint32_t)f2bf(v.y) << 16);
    o.y = (uint32_t)f2bf(v.z) | ((uint32_t)f2bf(v.w) << 16);
    ((uint2*)out)[i] = o;
  }
}

// ---------------- W[K][N] fp32 -> Wt[N][K] bf16, 64x64 tiles, vectorized ----------------
__global__ __launch_bounds__(256)
void transpose_conv_kernel(const float* __restrict__ W, uint16_t* __restrict__ Wt,
                           int K, int N) {
  // t32[n_local][k_pair]: packed pair (k even in low16, k odd in high16). stride 33 dodges conflicts.
  __shared__ uint32_t t32[64][33];
  const size_t mat = (size_t)K * N;
  const float*    Wp  = W  + mat * blockIdx.z;
  uint16_t*       Wtp = Wt + mat * blockIdx.z;
  const int n0 = blockIdx.x * 64, k0 = blockIdx.y * 64;
  const int tx = threadIdx.x & 15;     // n-quad
  const int ty = threadIdx.x >> 4;     // 0..15
  #pragma unroll
  for (int rb = 0; rb < 2; rb++) {
    const int kp = rb * 16 + ty;       // k-pair 0..31
    const int k  = k0 + kp * 2;
    const float4 r0 = *(const float4*)&Wp[(size_t)k * N + n0 + tx * 4];
    const float4 r1 = *(const float4*)&Wp[(size_t)(k + 1) * N + n0 + tx * 4];
    t32[tx * 4 + 0][kp] = (uint32_t)f2bf(r0.x) | ((uint32_t)f2bf(r1.x) << 16);
    t32[tx * 4 + 1][kp] = (uint32_t)f2bf(r0.y) | ((uint32_t)f2bf(r1.y) << 16);
    t32[tx * 4 + 2][kp] = (uint32_t)f2bf(r0.z) | ((uint32_t)f2bf(r1.z) << 16);
    t32[tx * 4 + 3][kp] = (uint32_t)f2bf(r0.w) | ((uint32_t)f2bf(r1.w) << 16);
  }
  __syncthreads();
  #pragma unroll
  for (int rb = 0; rb < 4; rb++) {
    const int nl = rb * 16 + ty;
    uint2 v; v.x = t32[nl][2 * tx]; v.y = t32[nl][2 * tx + 1];
    *(uint2*)&Wtp[(size_t)(n0 + nl) * K + k0 + tx * 4] = v;
  }
}

// ---------------- GEMM: C = [relu](A @ Wt^T + bias), 128x128xBK32, XCD-swizzled ----------------
// A: [rowsA][K] bf16 (optionally gathered via rowidx). Wt: [E][N][K] bf16 (pre-transposed).
// out: bf16 [Mpad][N]  or  (SCATTER) fp32 [B_ROWS][N] via rowidx with valid-mask.
// LDS k-chunk XOR swizzle: slot (row, s) holds global chunk s ^ sel(row),
// sel(row) = (row ^ (row>>2)) & 3 -> ds_read_b128 bank aliasing drops 8-way -> 2-way (free).
template<bool GATHER, bool EXPERT, bool RELU, bool SCATTER>
__global__ __launch_bounds__(256)
void gemm_kernel(const uint16_t* __restrict__ A, const uint16_t* __restrict__ W,
                 const float* __restrict__ bias, void* __restrict__ outp,
                 const int* __restrict__ rowidx, const int* __restrict__ texp,
                 const int* __restrict__ tval, int K) {
  __shared__ uint16_t sA[TM * BK];
  __shared__ uint16_t sB[TN * BK];

  const int tid = threadIdx.x;
  const int w = tid >> 6, l = tid & 63;

  // XCD-locality swizzle: consecutive linear blocks round-robin XCDs; give each
  // XCD a contiguous m-strip with all 8 n-tiles so A rows + the expert's W stay
  // in that XCD's L2.  gridDim.x = 8 * NT_M, NT_M % 8 == 0.
  const int lin = blockIdx.x;
  const int xcd = lin & 7;
  const int j   = lin >> 3;
  const int mpx = gridDim.x >> 6;          // NT_M / 8
  const int my  = xcd * mpx + (j >> 3);
  const int nx  = j & 7;
  const int m0 = my * TM;
  const int n0 = nx * TN;

  int e = 0, valid = TM;
  if (EXPERT) {
    e = texp[my];
    valid = tval[my];
    if (valid == 0) return;            // fully-padded tile: nothing downstream reads it unmasked
  }

  // staging: wave w fills 1KB LDS chunks; lane l -> row 16w+(l>>2), slot chunk l&3,
  // global chunk (l&3) ^ sel(row)
  const int lrow16 = l >> 2;
  const int row0   = 16 * w + lrow16;
  const int sel    = (row0 ^ (row0 >> 2)) & 3;       // same for row0+64
  const int koff   = ((l & 3) ^ sel) * 8;
  int ar0 = m0 + row0, ar1 = m0 + 64 + row0;
  if (GATHER) { ar0 = rowidx[ar0]; ar1 = rowidx[ar1]; }
  const uint16_t* srcA0 = A + (size_t)ar0 * K + koff;
  const uint16_t* srcA1 = A + (size_t)ar1 * K + koff;
  const uint16_t* Wb    = W + (size_t)e * N_DIM * K;
  const uint16_t* srcB0 = Wb + (size_t)(n0 + row0) * K + koff;
  const uint16_t* srcB1 = Wb + (size_t)(n0 + 64 + row0) * K + koff;
  uint16_t* ldsA0 = &sA[w * 512 + l * 8];
  uint16_t* ldsA1 = &sA[2048 + w * 512 + l * 8];
  uint16_t* ldsB0 = &sB[w * 512 + l * 8];
  uint16_t* ldsB1 = &sB[2048 + w * 512 + l * 8];

  const int wm = w >> 1, wn = w & 1;        // 2x2 waves, each 64x64
  const int q = l >> 4, r16 = l & 15;
  const int selr = (r16 ^ (r16 >> 2)) & 3;  // sel(rr) for rr = wm*64+i*16+r16 (i,wm drop out)

  f32x4 acc[4][4];
  #pragma unroll
  for (int i = 0; i < 4; i++)
    #pragma unroll
    for (int jj = 0; jj < 4; jj++) {
      f32x4 z = {0.f, 0.f, 0.f, 0.f};
      acc[i][jj] = z;
    }

  for (int k0 = 0; k0 < K; k0 += BK) {
    async_cp16(srcA0 + k0, ldsA0);
    async_cp16(srcA1 + k0, ldsA1);
    async_cp16(srcB0 + k0, ldsB0);
    async_cp16(srcB1 + k0, ldsB1);
    __syncthreads();                       // drains vmcnt -> LDS tiles complete
    bf16x8 af[4], bf[4];
    const int cq = (q ^ selr) * 8;
    #pragma unroll
    for (int i = 0; i < 4; i++) {
      af[i] = *(const bf16x8*)(&sA[(wm * 64 + i * 16 + r16) * BK + cq]);
      bf[i] = *(const bf16x8*)(&sB[(wn * 64 + i * 16 + r16) * BK + cq]);
    }
    #pragma unroll
    for (int i = 0; i < 4; i++)
      #pragma unroll
      for (int jj = 0; jj < 4; jj++)
        acc[i][jj] = __builtin_amdgcn_mfma_f32_16x16x32_bf16(af[i], bf[jj], acc[i][jj], 0, 0, 0);
    __syncthreads();                       // protect LDS before next overwrite
  }

  // epilogue: C/D layout col=lane&15, row=(lane>>4)*4+reg (m89/m91-verified)
  float bj[4];
  #pragma unroll
  for (int jj = 0; jj < 4; jj++)
    bj[jj] = bias[(size_t)e * N_DIM + n0 + wn * 64 + jj * 16 + r16];

  #pragma unroll
  for (int i = 0; i < 4; i++) {
    #pragma unroll
    for (int r = 0; r < 4; r++) {
      const int rl = wm * 64 + i * 16 + q * 4 + r;        // row within 128-tile
      if (SCATTER) {
        if (rl < valid) {
          const int orow = rowidx[m0 + rl];
          float* o = (float*)outp + (size_t)orow * N_DIM + n0 + wn * 64 + r16;
          #pragma unroll
          for (int jj = 0; jj < 4; jj++) {
            float v = acc[i][jj][r] + bj[jj];
            if (RELU) v = fmaxf(v, 0.f);
            o[jj * 16] = v;
          }
        }
      } else {
        uint16_t* o = (uint16_t*)outp + (size_t)(m0 + rl) * N_DIM + n0 + wn * 64 + r16;
        #pragma unroll
        for (int jj = 0; jj < 4; jj++) {
          float v = acc[i][jj][r] + bj[jj];
          if (RELU) v = fmaxf(v, 0.f);
          o[jj * 16] = f2bf(v);
        }
      }
    }
  }
}

// ---------------- launch ----------------
extern "C" void kernel_launch(void* const* d_in, const int* in_sizes, int n_in,
                              void* d_out, int out_size, void* d_ws, size_t ws_size,
                              hipStream_t stream) {
  const float* x   = (const float*)d_in[0];
  const int*   rel = (const int*)d_in[1];
  const float* W0  = (const float*)d_in[2];
  const float* b0  = (const float*)d_in[3];
  const float* W1  = (const float*)d_in[4];
  const float* b1  = (const float*)d_in[5];
  const float* RW1 = (const float*)d_in[6];
  const float* Rb1 = (const float*)d_in[7];
  const float* RW2 = (const float*)d_in[8];
  const float* Rb2 = (const float*)d_in[9];
  const float* RW3 = (const float*)d_in[10];
  const float* Rb3 = (const float*)d_in[11];
  float* out = (float*)d_out;

  // workspace layout (bytes): xb 16MB | wt 32MB | ha 36MB | hb 36MB | rowidx/meta
  char* ws = (char*)d_ws;
  uint16_t* xb = (uint16_t*)(ws);
  uint16_t* wt = (uint16_t*)(ws + (size_t)(16u << 20));
  uint16_t* ha = (uint16_t*)(ws + (size_t)(48u << 20));
  uint16_t* hb = (uint16_t*)(ws + (size_t)(84u << 20));
  int* rowidx = (int*)(ws + (size_t)(120u << 20));
  int* texp   = rowidx + PADDED_ROWS;
  int* tval   = texp + MAX_TILES;

  const dim3 blk(256);
  const dim3 gDense(8 * (B_ROWS / TM));           // 1D, XCD-swizzled in-kernel
  const dim3 gRel(8 * MAX_TILES);

  setup_kernel<<<dim3(1), blk, 0, stream>>>(rel, rowidx, texp, tval);
  conv_x_kernel<<<dim3((B_ROWS * D_IN) / 4 / 256), blk, 0, stream>>>(x, xb, (B_ROWS * D_IN) / 4);

  // L0: h = relu(x @ W0 + b0), K=512
  transpose_conv_kernel<<<dim3(N_DIM / 64, D_IN / 64, 1), blk, 0, stream>>>(W0, wt, D_IN, N_DIM);
  gemm_kernel<false, false, true, false><<<gDense, blk, 0, stream>>>(
      xb, wt, b0, ha, nullptr, nullptr, nullptr, D_IN);

  // L1: h = relu(h @ W1 + b1), K=1024
  transpose_conv_kernel<<<dim3(N_DIM / 64, N_DIM / 64, 1), blk, 0, stream>>>(W1, wt, N_DIM, N_DIM);
  gemm_kernel<false, false, true, false><<<gDense, blk, 0, stream>>>(
      ha, wt, b1, hb, nullptr, nullptr, nullptr, N_DIM);

  // L2: gather rows by relation, relu(h @ RW1[r] + Rb1[r]) -> padded layout
  transpose_conv_kernel<<<dim3(N_DIM / 64, N_DIM / 64, NREL), blk, 0, stream>>>(RW1, wt, N_DIM, N_DIM);
  gemm_kernel<true, true, true, false><<<gRel, blk, 0, stream>>>(
      hb, wt, Rb1, ha, rowidx, texp, tval, N_DIM);

  // L3: relu(h @ RW2[r] + Rb2[r]) in padded layout
  transpose_conv_kernel<<<dim3(N_DIM / 64, N_DIM / 64, NREL), blk, 0, stream>>>(RW2, wt, N_DIM, N_DIM);
  gemm_kernel<false, true, true, false><<<gRel, blk, 0, stream>>>(
      ha, wt, Rb2, hb, rowidx, texp, tval, N_DIM);

  // L4: out[orig_row] = h @ RW3[r] + Rb3[r], fp32 scatter, no relu
  transpose_conv_kernel<<<dim3(N_DIM / 64, N_DIM / 64, NREL), blk, 0, stream>>>(RW3, wt, N_DIM, N_DIM);
  gemm_kernel<false, true, false, true><<<gRel, blk, 0, stream>>>(
      hb, wt, Rb3, out, rowidx, texp, tval, N_DIM);

  (void)in_sizes; (void)n_in; (void)out_size; (void)ws_size;
}

// Round 3
// 520.119 us; speedup vs baseline: 1.2181x; 1.1039x over previous
//
#include <hip/hip_runtime.h>
#include <stdint.h>

// ---------------- problem constants ----------------
#define B_ROWS   16384
#define D_IN     512
#define N_DIM    1024
#define NREL     16
#define TM       128
#define TN       128
#define BK       32
#define MAX_TILES 144                 // <= B_ROWS/TM + NREL-1 padding tiles
#define PADDED_ROWS (MAX_TILES * TM)  // 18432

typedef __bf16 bf16x8 __attribute__((ext_vector_type(8)));
typedef float  f32x4  __attribute__((ext_vector_type(4)));

__device__ __forceinline__ uint16_t f2bf(float f) {
  union { float f; uint32_t u; } v; v.f = f;
  return (uint16_t)((v.u + 0x7fffu + ((v.u >> 16) & 1u)) >> 16);   // RNE
}

// async global->LDS 16B copy. LDS dest must be (wave-uniform base + lane*16).
__device__ __forceinline__ void async_cp16(const uint16_t* g, uint16_t* l) {
  __builtin_amdgcn_global_load_lds(
      (__attribute__((address_space(1))) void*)(g),
      (__attribute__((address_space(3))) void*)(l), 16, 0, 0);
}

// ---------------- setup: histogram relations, build padded permutation ----------------
__global__ void setup_kernel(const int* __restrict__ rel, int* __restrict__ rowidx,
                             int* __restrict__ texp, int* __restrict__ tval) {
  __shared__ int cnt[NREL], segstart[NREL], cursor[NREL];
  const int t = threadIdx.x;
  const int nt_ = blockDim.x;
  if (t < NREL) { cnt[t] = 0; cursor[t] = 0; }
  __syncthreads();
  for (int i = t; i < B_ROWS; i += nt_) atomicAdd(&cnt[rel[i]], 1);
  __syncthreads();
  if (t == 0) {
    int slot = 0, tile = 0;
    for (int r = 0; r < NREL; r++) {
      segstart[r] = slot;
      const int c = cnt[r];
      const int nt = (c + TM - 1) / TM;
      for (int k = 0; k < nt; k++) {
        texp[tile + k] = r;
        const int rem = c - k * TM;
        tval[tile + k] = rem < TM ? rem : TM;
      }
      tile += nt; slot += nt * TM;
    }
    for (; tile < MAX_TILES; tile++) { texp[tile] = 0; tval[tile] = 0; }
  }
  __syncthreads();
  for (int i = t; i < PADDED_ROWS; i += nt_) rowidx[i] = 0;  // padded slots -> row 0 (safe loads)
  __syncthreads();
  for (int i = t; i < B_ROWS; i += nt_) {
    const int r = rel[i];
    const int p = atomicAdd(&cursor[r], 1);
    rowidx[segstart[r] + p] = i;
  }
}

// ---------------- fp32 -> bf16 elementwise (x) ----------------
__global__ void conv_x_kernel(const float* __restrict__ in, uint16_t* __restrict__ out, int n4) {
  const int i = blockIdx.x * blockDim.x + threadIdx.x;
  if (i < n4) {
    const float4 v = ((const float4*)in)[i];
    uint2 o;
    o.x = (uint32_t)f2bf(v.x) | ((uint32_t)f2bf(v.y) << 16);
    o.y = (uint32_t)f2bf(v.z) | ((uint32_t)f2bf(v.w) << 16);
    ((uint2*)out)[i] = o;
  }
}

// ---------------- W[K][N] fp32 -> Wt[N][K] bf16, 64x64 tiles, vectorized ----------------
__global__ __launch_bounds__(256)
void transpose_conv_kernel(const float* __restrict__ W, uint16_t* __restrict__ Wt,
                           int K, int N) {
  // t32[n_local][k_pair]: packed pair (k even in low16, k odd in high16). stride 33 dodges conflicts.
  __shared__ uint32_t t32[64][33];
  const size_t mat = (size_t)K * N;
  const float*    Wp  = W  + mat * blockIdx.z;
  uint16_t*       Wtp = Wt + mat * blockIdx.z;
  const int n0 = blockIdx.x * 64, k0 = blockIdx.y * 64;
  const int tx = threadIdx.x & 15;     // n-quad
  const int ty = threadIdx.x >> 4;     // 0..15
  #pragma unroll
  for (int rb = 0; rb < 2; rb++) {
    const int kp = rb * 16 + ty;       // k-pair 0..31
    const int k  = k0 + kp * 2;
    const float4 r0 = *(const float4*)&Wp[(size_t)k * N + n0 + tx * 4];
    const float4 r1 = *(const float4*)&Wp[(size_t)(k + 1) * N + n0 + tx * 4];
    t32[tx * 4 + 0][kp] = (uint32_t)f2bf(r0.x) | ((uint32_t)f2bf(r1.x) << 16);
    t32[tx * 4 + 1][kp] = (uint32_t)f2bf(r0.y) | ((uint32_t)f2bf(r1.y) << 16);
    t32[tx * 4 + 2][kp] = (uint32_t)f2bf(r0.z) | ((uint32_t)f2bf(r1.z) << 16);
    t32[tx * 4 + 3][kp] = (uint32_t)f2bf(r0.w) | ((uint32_t)f2bf(r1.w) << 16);
  }
  __syncthreads();
  #pragma unroll
  for (int rb = 0; rb < 4; rb++) {
    const int nl = rb * 16 + ty;
    uint2 v; v.x = t32[nl][2 * tx]; v.y = t32[nl][2 * tx + 1];
    *(uint2*)&Wtp[(size_t)(n0 + nl) * K + k0 + tx * 4] = v;
  }
}

// ---------------- GEMM: C = [relu](A @ Wt^T + bias), 128x128xBK32 ----------------
// XCD-swizzled grid; LDS double-buffered K-loop with fine-grained vmcnt(4)
// (AITER-style: prefetch DMAs for tile k+1 stay in flight across the barrier).
template<bool GATHER, bool EXPERT, bool RELU, bool SCATTER>
__global__ __launch_bounds__(256)
void gemm_kernel(const uint16_t* __restrict__ A, const uint16_t* __restrict__ W,
                 const float* __restrict__ bias, void* __restrict__ outp,
                 const int* __restrict__ rowidx, const int* __restrict__ texp,
                 const int* __restrict__ tval, int K) {
  __shared__ uint16_t sA[2][TM * BK];
  __shared__ uint16_t sB[2][TN * BK];

  const int tid = threadIdx.x;
  const int w = tid >> 6, l = tid & 63;

  // XCD-locality swizzle: gridDim.x = 8 * NT_M, NT_M % 8 == 0. Each XCD gets a
  // contiguous m-strip with all 8 n-tiles -> A rows + the expert's W stay in L2.
  const int lin = blockIdx.x;
  const int xcd = lin & 7;
  const int j   = lin >> 3;
  const int mpx = gridDim.x >> 6;          // NT_M / 8
  const int my  = xcd * mpx + (j >> 3);
  const int nx  = j & 7;
  const int m0 = my * TM;
  const int n0 = nx * TN;

  int e = 0, valid = TM;
  if (EXPERT) {
    e = texp[my];
    valid = tval[my];
    if (valid == 0) return;            // block-uniform: no barrier divergence
  }

  // staging: wave w fills 1KB LDS chunks; lane l -> row 16w+(l>>2), slot chunk l&3,
  // global chunk (l&3) ^ sel(row)  [XOR swizzle keeps ds_read_b128 conflict-free]
  const int row0   = 16 * w + (l >> 2);
  const int sel    = (row0 ^ (row0 >> 2)) & 3;       // same for row0+64
  const int koff   = ((l & 3) ^ sel) * 8;
  int ar0 = m0 + row0, ar1 = m0 + 64 + row0;
  if (GATHER) { ar0 = rowidx[ar0]; ar1 = rowidx[ar1]; }
  const uint16_t* srcA0 = A + (size_t)ar0 * K + koff;
  const uint16_t* srcA1 = A + (size_t)ar1 * K + koff;
  const uint16_t* Wb    = W + (size_t)e * N_DIM * K;
  const uint16_t* srcB0 = Wb + (size_t)(n0 + row0) * K + koff;
  const uint16_t* srcB1 = Wb + (size_t)(n0 + 64 + row0) * K + koff;
  uint16_t* ldsA0 = &sA[0][w * 512 + l * 8];
  uint16_t* ldsA1 = &sA[0][2048 + w * 512 + l * 8];
  uint16_t* ldsB0 = &sB[0][w * 512 + l * 8];
  uint16_t* ldsB1 = &sB[0][2048 + w * 512 + l * 8];

  const int wm = w >> 1, wn = w & 1;        // 2x2 waves, each 64x64
  const int q = l >> 4, r16 = l & 15;
  const int selr = (r16 ^ (r16 >> 2)) & 3;  // sel(row) for read rows (i,wm drop out mod 4)
  const int cq = (q ^ selr) * 8;

  f32x4 acc[4][4];
  #pragma unroll
  for (int i = 0; i < 4; i++)
    #pragma unroll
    for (int jj = 0; jj < 4; jj++) {
      f32x4 z = {0.f, 0.f, 0.f, 0.f};
      acc[i][jj] = z;
    }

  const int nIter = K / BK;

  // prologue: stage tile 0 into buffer 0
  async_cp16(srcA0, ldsA0);
  async_cp16(srcA1, ldsA1);
  async_cp16(srcB0, ldsB0);
  async_cp16(srcB1, ldsB1);

  for (int k = 0; k < nIter; k++) {
    const int cur = k & 1;
    if (k + 1 < nIter) {
      // prefetch tile k+1 into the other buffer (4096 elements = 8KB apart)
      const int koff2 = (k + 1) * BK;
      const int boff  = (cur ^ 1) * 4096;
      async_cp16(srcA0 + koff2, ldsA0 + boff);
      async_cp16(srcA1 + koff2, ldsA1 + boff);
      async_cp16(srcB0 + koff2, ldsB0 + boff);
      async_cp16(srcB1 + koff2, ldsB1 + boff);
      // wait only the oldest 4 (tile k); tile k+1 stays in flight across the barrier
      asm volatile("s_waitcnt vmcnt(4)" ::: "memory");
    } else {
      asm volatile("s_waitcnt vmcnt(0)" ::: "memory");
    }
    __builtin_amdgcn_s_barrier();      // tile k resident for all waves

    bf16x8 af[4], bf[4];
    #pragma unroll
    for (int i = 0; i < 4; i++) {
      af[i] = *(const bf16x8*)(&sA[cur][(wm * 64 + i * 16 + r16) * BK + cq]);
      bf[i] = *(const bf16x8*)(&sB[cur][(wn * 64 + i * 16 + r16) * BK + cq]);
    }
    #pragma unroll
    for (int i = 0; i < 4; i++)
      #pragma unroll
      for (int jj = 0; jj < 4; jj++)
        acc[i][jj] = __builtin_amdgcn_mfma_f32_16x16x32_bf16(af[i], bf[jj], acc[i][jj], 0, 0, 0);

    // reads of buf[cur] are consumed by the MFMAs above (lgkm drained by use);
    // this barrier protects buf[cur] from tile k+2's DMA issued next iteration.
    __builtin_amdgcn_s_barrier();
  }

  // epilogue: C/D layout col=lane&15, row=(lane>>4)*4+reg (m89/m91-verified)
  float bj[4];
  #pragma unroll
  for (int jj = 0; jj < 4; jj++)
    bj[jj] = bias[(size_t)e * N_DIM + n0 + wn * 64 + jj * 16 + r16];

  #pragma unroll
  for (int i = 0; i < 4; i++) {
    #pragma unroll
    for (int r = 0; r < 4; r++) {
      const int rl = wm * 64 + i * 16 + q * 4 + r;        // row within 128-tile
      if (SCATTER) {
        if (rl < valid) {
          const int orow = rowidx[m0 + rl];
          float* o = (float*)outp + (size_t)orow * N_DIM + n0 + wn * 64 + r16;
          #pragma unroll
          for (int jj = 0; jj < 4; jj++) {
            float v = acc[i][jj][r] + bj[jj];
            if (RELU) v = fmaxf(v, 0.f);
            o[jj * 16] = v;
          }
        }
      } else {
        uint16_t* o = (uint16_t*)outp + (size_t)(m0 + rl) * N_DIM + n0 + wn * 64 + r16;
        #pragma unroll
        for (int jj = 0; jj < 4; jj++) {
          float v = acc[i][jj][r] + bj[jj];
          if (RELU) v = fmaxf(v, 0.f);
          o[jj * 16] = f2bf(v);
        }
      }
    }
  }
}

// ---------------- launch ----------------
extern "C" void kernel_launch(void* const* d_in, const int* in_sizes, int n_in,
                              void* d_out, int out_size, void* d_ws, size_t ws_size,
                              hipStream_t stream) {
  const float* x   = (const float*)d_in[0];
  const int*   rel = (const int*)d_in[1];
  const float* W0  = (const float*)d_in[2];
  const float* b0  = (const float*)d_in[3];
  const float* W1  = (const float*)d_in[4];
  const float* b1  = (const float*)d_in[5];
  const float* RW1 = (const float*)d_in[6];
  const float* Rb1 = (const float*)d_in[7];
  const float* RW2 = (const float*)d_in[8];
  const float* Rb2 = (const float*)d_in[9];
  const float* RW3 = (const float*)d_in[10];
  const float* Rb3 = (const float*)d_in[11];
  float* out = (float*)d_out;

  // workspace layout (bytes): xb 16MB | wt 32MB | ha 36MB | hb 36MB | rowidx/meta
  char* ws = (char*)d_ws;
  uint16_t* xb = (uint16_t*)(ws);
  uint16_t* wt = (uint16_t*)(ws + (size_t)(16u << 20));
  uint16_t* ha = (uint16_t*)(ws + (size_t)(48u << 20));
  uint16_t* hb = (uint16_t*)(ws + (size_t)(84u << 20));
  int* rowidx = (int*)(ws + (size_t)(120u << 20));
  int* texp   = rowidx + PADDED_ROWS;
  int* tval   = texp + MAX_TILES;

  const dim3 blk(256);
  const dim3 gDense(8 * (B_ROWS / TM));           // 1D, XCD-swizzled in-kernel
  const dim3 gRel(8 * MAX_TILES);

  setup_kernel<<<dim3(1), dim3(1024), 0, stream>>>(rel, rowidx, texp, tval);
  conv_x_kernel<<<dim3((B_ROWS * D_IN) / 4 / 256), blk, 0, stream>>>(x, xb, (B_ROWS * D_IN) / 4);

  // L0: h = relu(x @ W0 + b0), K=512
  transpose_conv_kernel<<<dim3(N_DIM / 64, D_IN / 64, 1), blk, 0, stream>>>(W0, wt, D_IN, N_DIM);
  gemm_kernel<false, false, true, false><<<gDense, blk, 0, stream>>>(
      xb, wt, b0, ha, nullptr, nullptr, nullptr, D_IN);

  // L1: h = relu(h @ W1 + b1), K=1024
  transpose_conv_kernel<<<dim3(N_DIM / 64, N_DIM / 64, 1), blk, 0, stream>>>(W1, wt, N_DIM, N_DIM);
  gemm_kernel<false, false, true, false><<<gDense, blk, 0, stream>>>(
      ha, wt, b1, hb, nullptr, nullptr, nullptr, N_DIM);

  // L2: gather rows by relation, relu(h @ RW1[r] + Rb1[r]) -> padded layout
  transpose_conv_kernel<<<dim3(N_DIM / 64, N_DIM / 64, NREL), blk, 0, stream>>>(RW1, wt, N_DIM, N_DIM);
  gemm_kernel<true, true, true, false><<<gRel, blk, 0, stream>>>(
      hb, wt, Rb1, ha, rowidx, texp, tval, N_DIM);

  // L3: relu(h @ RW2[r] + Rb2[r]) in padded layout
  transpose_conv_kernel<<<dim3(N_DIM / 64, N_DIM / 64, NREL), blk, 0, stream>>>(RW2, wt, N_DIM, N_DIM);
  gemm_kernel<false, true, true, false><<<gRel, blk, 0, stream>>>(
      ha, wt, Rb2, hb, rowidx, texp, tval, N_DIM);

  // L4: out[orig_row] = h @ RW3[r] + Rb3[r], fp32 scatter, no relu
  transpose_conv_kernel<<<dim3(N_DIM / 64, N_DIM / 64, NREL), blk, 0, stream>>>(RW3, wt, N_DIM, N_DIM);
  gemm_kernel<false, true, false, true><<<gRel, blk, 0, stream>>>(
      hb, wt, Rb3, out, rowidx, texp, tval, N_DIM);

  (void)in_sizes; (void)n_in; (void)out_size; (void)ws_size;
}